// Round 5
// baseline (130.083 us; speedup 1.0000x reference)
//
#include <hip/hip_runtime.h>
#include <hip/hip_bf16.h>

// DenseGraphSimpleOpEdgeFlow: out[b,i,f] = sum_j attn[b,i,j,f]*support[b,j,f] + support[b,i,f]
//   support = inputs @ weight  (fp32)
//   attn = mask(sigmoid(op_emb' @ attn_w + attn_b)); diagonal op_emb replaced by self_op_emb,
//   adj' = adj + I; adj'==0 -> 0, adj'==1 (SKIP) -> 1, else sigmoid.
// R5: R2-R4 were convoy-bound (~89us regardless of memory residency: barrier-lockstep 4-wave
// blocks, 20% occupancy, VALUBusy 24%). This version has NO LDS and NO barriers: one block
// per (b,i), 4 fully independent waves; wave w owns f in [32w,32w+32). A-fragments are read
// straight from global (each lane 8 contiguous floats of its j-row; tile bytes hit L1 for
// waves 2..4); adj codes per-lane via uint4 loads; diagonal handled by per-block a_self
// (sigmoid(self_op.W+b) is (b,i)-independent). Full unroll over the 6 j-tiles gives 6
// independent load->MFMA->sigmoid chains per wave; no inter-wave sync anywhere.
// Requires ws_size >= 64*96*128*4 = 3,145,728 bytes (support scratch).

#define B_ 64
#define N_ 96
#define F_ 128
#define D_ 48

typedef __attribute__((ext_vector_type(8))) short short8;
typedef __attribute__((ext_vector_type(4))) float f32x4;

#if __has_builtin(__builtin_amdgcn_exp2f)
#define EXP2(x) __builtin_amdgcn_exp2f(x)
#else
#define EXP2(x) exp2f(x)
#endif

__device__ __forceinline__ unsigned bfbits(float x) {
    union { __hip_bfloat16 h; unsigned short u; } cv;
    cv.h = __float2bfloat16(x);
    return (unsigned)cv.u;
}
__device__ __forceinline__ float bf2f(unsigned short u) {
    union { float f; unsigned v; } cv;
    cv.v = ((unsigned)u) << 16;
    return cv.f;
}

// ---------------- Kernel 1: support = inputs @ weight  [6144,128]@[128,128] fp32 ----------------
__global__ __launch_bounds__(256, 4) void support_kernel(
    const float* __restrict__ inputs, const float* __restrict__ weight,
    float* __restrict__ support)
{
    __shared__ float in_lds[16 * F_];
    const int tid = threadIdx.x;
    const int row0 = blockIdx.x * 16;
    ((float4*)in_lds)[tid]       = ((const float4*)(inputs + (size_t)row0 * F_))[tid];
    ((float4*)in_lds)[tid + 256] = ((const float4*)(inputs + (size_t)row0 * F_))[tid + 256];
    __syncthreads();
    const int rl = tid >> 4, f0 = (tid & 15) * 8;
    float acc[8] = {0.f,0.f,0.f,0.f,0.f,0.f,0.f,0.f};
    #pragma unroll 4
    for (int k = 0; k < F_; ++k) {
        const float a = in_lds[rl * F_ + k];
        const float4 w0 = *(const float4*)(weight + k * F_ + f0);
        const float4 w1 = *(const float4*)(weight + k * F_ + f0 + 4);
        acc[0] += a * w0.x; acc[1] += a * w0.y; acc[2] += a * w0.z; acc[3] += a * w0.w;
        acc[4] += a * w1.x; acc[5] += a * w1.y; acc[6] += a * w1.z; acc[7] += a * w1.w;
    }
    float* o = support + (size_t)(row0 + rl) * F_ + f0;
    *(float4*)o       = make_float4(acc[0], acc[1], acc[2], acc[3]);
    *(float4*)(o + 4) = make_float4(acc[4], acc[5], acc[6], acc[7]);
}

// ---------------- Kernel 2: fused attn-GEMM + mask + weighted reduce + residual ----------------
// MFMA 16x16x32 k-slot fill d = ks*32 + lg*8 + e, identical for A and B fragments (the
// physical-k permutation cancels). C/D layout (HW-verified): col = lane&15 (-> f),
// row = (lane>>4)*4 + reg (-> j).
__global__ __launch_bounds__(256, 2) void fused_kernel(
    const float* __restrict__ op_emb,
    const unsigned* __restrict__ adjw,      // raw 32-bit view of adj (int32 or int64)
    const float* __restrict__ attn_w,
    const float* __restrict__ attn_b,
    const float* __restrict__ self_op,
    const float* __restrict__ support,
    float* __restrict__ out)
{
    const int tid  = threadIdx.x;
    const int lane = tid & 63;
    const int wv   = tid >> 6;      // wave 0..3 -> f-slice
    const int lg   = lane >> 4;     // k-slot group / j-subgroup 0..3
    const int lm   = lane & 15;

    const int blk = blockIdx.x;
    const int b   = blk / N_;
    const int i   = blk - b * N_;
    const size_t rb = (size_t)(b * N_ + i) * N_;     // adj row base (elements)
    const float* arow = op_emb + rb * D_;            // A-tile base

    const float kNL2E = -1.44269504088896f;   // -log2(e): exp(-x) = exp2(kNL2E*x)

    // --- adj dtype sniff: int64 little-endian has all-zero high words (values 0..4) ---
    const unsigned probe = adjw[2 * lane + 1];
    const bool use32 = __any(probe != 0);   // wave-uniform; identical across waves

    // --- B fragments (attn_w pre-scaled by -log2e) + bias, registers ---
    short8 bfrag[2][2];
    float  bbias[2];
    #pragma unroll
    for (int t = 0; t < 2; ++t) {
        const int f = (2 * wv + t) * 16 + lm;
        bbias[t] = attn_b[f] * kNL2E;
        #pragma unroll
        for (int ks = 0; ks < 2; ++ks) {
            short8 v;
            #pragma unroll
            for (int e = 0; e < 8; ++e) {
                const int d = ks * 32 + lg * 8 + e;
                v[e] = (d < D_) ? (short)bfbits(attn_w[d * F_ + f] * kNL2E) : (short)0;
            }
            bfrag[t][ks] = v;
        }
    }

    // --- a_self[t] = sigmoid(self_op . attn_w[:,f] + b[f]) -- (b,i)-independent ---
    float a_self[2];
    {
        float part[2] = {0.f, 0.f};
        #pragma unroll
        for (int ks = 0; ks < 2; ++ks) {
            #pragma unroll
            for (int e = 0; e < 8; ++e) {
                const int d = ks * 32 + lg * 8 + e;
                const float sv = (d < D_) ? self_op[d] : 0.f;
                part[0] = __builtin_fmaf(bf2f((unsigned short)bfrag[0][ks][e]), sv, part[0]);
                part[1] = __builtin_fmaf(bf2f((unsigned short)bfrag[1][ks][e]), sv, part[1]);
            }
        }
        #pragma unroll
        for (int t = 0; t < 2; ++t) {
            float v = part[t];
            v += __shfl_xor(v, 16);
            v += __shfl_xor(v, 32);          // sum over the 4 lg groups -> full 48-dot
            a_self[t] = __builtin_amdgcn_rcpf(1.f + EXP2(v + bbias[t]));
        }
    }

    // --- support fragments, registers (layout matches C/D frag) ---
    const float* srow = support + (size_t)b * N_ * F_;
    float sfrag[6][4][2];
    #pragma unroll
    for (int mt = 0; mt < 6; ++mt)
        #pragma unroll
        for (int r = 0; r < 4; ++r)
            #pragma unroll
            for (int t = 0; t < 2; ++t)
                sfrag[mt][r][t] = srow[(size_t)(mt * 16 + lg * 4 + r) * F_ + (2 * wv + t) * 16 + lm];

    // --- main: 6 independent j-tiles; A straight from global; no barriers ---
    float osum[2] = {0.f, 0.f};
    #pragma unroll
    for (int mt = 0; mt < 6; ++mt) {
        // adj codes for j = mt*16 + lg*4 + r, r=0..3 (vector load, lane-local)
        int araw[4];
        {
            const size_t j0 = (size_t)mt * 16 + lg * 4;
            if (use32) {
                const uint4 v = *(const uint4*)(adjw + rb + j0);
                araw[0] = (int)v.x; araw[1] = (int)v.y; araw[2] = (int)v.z; araw[3] = (int)v.w;
            } else {
                const uint4 v0 = *(const uint4*)(adjw + 2 * (rb + j0));
                const uint4 v1 = *(const uint4*)(adjw + 2 * (rb + j0) + 4);
                araw[0] = (int)v0.x; araw[1] = (int)v0.z; araw[2] = (int)v1.x; araw[3] = (int)v1.z;
            }
        }
        // A fragments: lane (lg,lm) reads 8 contiguous floats of row j = mt*16+lm
        const float* rp = arow + (size_t)(mt * 16 + lm) * D_;
        const float4 fa0 = *(const float4*)(rp + lg * 8);
        const float4 fa1 = *(const float4*)(rp + lg * 8 + 4);
        float4 fb0 = make_float4(0.f, 0.f, 0.f, 0.f), fb1 = fb0;
        if (lg < 2) {                         // ks1 covers d in [32,48); lg>=2 is the zero pad
            fb0 = *(const float4*)(rp + 32 + lg * 8);
            fb1 = *(const float4*)(rp + 32 + lg * 8 + 4);
        }
        short8 a0, a1;
        a0[0] = (short)bfbits(fa0.x); a0[1] = (short)bfbits(fa0.y);
        a0[2] = (short)bfbits(fa0.z); a0[3] = (short)bfbits(fa0.w);
        a0[4] = (short)bfbits(fa1.x); a0[5] = (short)bfbits(fa1.y);
        a0[6] = (short)bfbits(fa1.z); a0[7] = (short)bfbits(fa1.w);
        a1[0] = (short)bfbits(fb0.x); a1[1] = (short)bfbits(fb0.y);
        a1[2] = (short)bfbits(fb0.z); a1[3] = (short)bfbits(fb0.w);
        a1[4] = (short)bfbits(fb1.x); a1[5] = (short)bfbits(fb1.y);
        a1[6] = (short)bfbits(fb1.z); a1[7] = (short)bfbits(fb1.w);

        f32x4 acc0 = (f32x4){bbias[0], bbias[0], bbias[0], bbias[0]};
        f32x4 acc1 = (f32x4){bbias[1], bbias[1], bbias[1], bbias[1]};
        acc0 = __builtin_amdgcn_mfma_f32_16x16x32_bf16(a0, bfrag[0][0], acc0, 0, 0, 0);
        acc0 = __builtin_amdgcn_mfma_f32_16x16x32_bf16(a1, bfrag[0][1], acc0, 0, 0, 0);
        acc1 = __builtin_amdgcn_mfma_f32_16x16x32_bf16(a0, bfrag[1][0], acc1, 0, 0, 0);
        acc1 = __builtin_amdgcn_mfma_f32_16x16x32_bf16(a1, bfrag[1][1], acc1, 0, 0, 0);

        #pragma unroll
        for (int r = 0; r < 4; ++r) {
            const int j = mt * 16 + lg * 4 + r;
            const int a = araw[r];
            const bool diag = (j == i);
            // off-diag: a>=2 -> sigmoid, a==1 -> 1, a==0 -> 0
            // diag (a'=a+1, self row): a==0 -> 1, else -> a_self
            const float mx = (!diag && a >= 2) ? 1.f : 0.f;
            const float my = (diag ? (a == 0) : (a == 1)) ? 1.f : 0.f;
            const float mz = (diag && a != 0) ? 1.f : 0.f;
            const float base0 = __builtin_fmaf(mz, a_self[0], my);
            const float base1 = __builtin_fmaf(mz, a_self[1], my);
            // acc = -log2e*(op_emb.attn_w + b)  ->  sigmoid = rcp(1 + exp2(acc))
            const float sig0 = __builtin_amdgcn_rcpf(1.f + EXP2(acc0[r]));
            const float sig1 = __builtin_amdgcn_rcpf(1.f + EXP2(acc1[r]));
            const float av0 = __builtin_fmaf(mx, sig0, base0);
            const float av1 = __builtin_fmaf(mx, sig1, base1);
            osum[0] = __builtin_fmaf(av0, sfrag[mt][r][0], osum[0]);
            osum[1] = __builtin_fmaf(av1, sfrag[mt][r][1], osum[1]);
        }
    }

    // --- output: lanes {l, l+16, l+32, l+48} hold disjoint j-subsets of the same f ---
    #pragma unroll
    for (int t = 0; t < 2; ++t) {
        float v = osum[t];
        v += __shfl_xor(v, 16);
        v += __shfl_xor(v, 32);
        if (lg == 0) {
            const int f = (2 * wv + t) * 16 + lm;
            out[(size_t)(b * N_ + i) * F_ + f] = v + srow[(size_t)i * F_ + f];
        }
    }
}

extern "C" void kernel_launch(void* const* d_in, const int* in_sizes, int n_in,
                              void* d_out, int out_size, void* d_ws, size_t ws_size,
                              hipStream_t stream) {
    const float*    inputs  = (const float*)d_in[0];
    const unsigned* adjw    = (const unsigned*)d_in[1];
    const float*    op_emb  = (const float*)d_in[2];
    const float*    weight  = (const float*)d_in[3];
    const float*    attn_w  = (const float*)d_in[4];
    const float*    attn_b  = (const float*)d_in[5];
    const float*    self_op = (const float*)d_in[6];
    float* out     = (float*)d_out;
    float* support = (float*)d_ws;  // 6144*128 fp32 = 3,145,728 bytes

    support_kernel<<<(B_ * N_) / 16, 256, 0, stream>>>(inputs, weight, support);
    fused_kernel<<<B_ * N_, 256, 0, stream>>>(op_emb, adjw, attn_w, attn_b, self_op,
                                              support, out);
}

// Round 6
// 75.325 us; speedup vs baseline: 1.7270x; 1.7270x over previous
//
#include <hip/hip_runtime.h>
#include <hip/hip_bf16.h>

// DenseGraphSimpleOpEdgeFlow: out[b,i,f] = sum_j attn[b,i,j,f]*support[b,j,f] + support[b,i,f]
//   support = inputs @ weight  (fp32)
//   attn = mask(sigmoid(op_emb' @ attn_w + attn_b)); diagonal op_emb replaced by self_op_emb,
//   adj' = adj + I; adj'==0 -> 0, adj'==1 (SKIP) -> 1, else sigmoid.
// R6: grid = 512 blocks (exactly 2/CU), G_=12 i's per block. R2-R5 showed wall time invariant
// to memory residency & barrier removal with all pipes <30% busy: the structure never reached
// pipeline steady state (per-block preamble of ~90 VMEM loads re-paid 1024-6144x; only 4-6
// shallow phases per block). This round amortizes the preamble 2x more and deepens the
// per-block phase pipeline to 12, with 2 co-resident blocks/CU covering barrier drains.
// g-loop is unroll(1) to avoid 12x code bloat (I$).
// Requires ws_size >= 64*96*128*4 = 3,145,728 bytes (support scratch).

#define B_ 64
#define N_ 96
#define F_ 128
#define D_ 48
#define G_ 12
#define NGRP (N_ / G_)   // 8 groups -> grid = 64*8 = 512 blocks = 2/CU

typedef __attribute__((ext_vector_type(8))) short short8;
typedef __attribute__((ext_vector_type(4))) float f32x4;

#if __has_builtin(__builtin_amdgcn_exp2f)
#define EXP2(x) __builtin_amdgcn_exp2f(x)
#else
#define EXP2(x) exp2f(x)
#endif

__device__ __forceinline__ unsigned bfbits(float x) {
    union { __hip_bfloat16 h; unsigned short u; } cv;
    cv.h = __float2bfloat16(x);
    return (unsigned)cv.u;
}
__device__ __forceinline__ float bf2f(unsigned short u) {
    union { float f; unsigned v; } cv;
    cv.v = ((unsigned)u) << 16;
    return cv.f;
}

// ---------------- Kernel 1: support = inputs @ weight  [6144,128]@[128,128] fp32 ----------------
__global__ __launch_bounds__(256, 4) void support_kernel(
    const float* __restrict__ inputs, const float* __restrict__ weight,
    float* __restrict__ support)
{
    __shared__ float in_lds[16 * F_];
    const int tid = threadIdx.x;
    const int row0 = blockIdx.x * 16;
    ((float4*)in_lds)[tid]       = ((const float4*)(inputs + (size_t)row0 * F_))[tid];
    ((float4*)in_lds)[tid + 256] = ((const float4*)(inputs + (size_t)row0 * F_))[tid + 256];
    __syncthreads();
    const int rl = tid >> 4, f0 = (tid & 15) * 8;
    float acc[8] = {0.f,0.f,0.f,0.f,0.f,0.f,0.f,0.f};
    #pragma unroll 4
    for (int k = 0; k < F_; ++k) {
        const float a = in_lds[rl * F_ + k];
        const float4 w0 = *(const float4*)(weight + k * F_ + f0);
        const float4 w1 = *(const float4*)(weight + k * F_ + f0 + 4);
        acc[0] += a * w0.x; acc[1] += a * w0.y; acc[2] += a * w0.z; acc[3] += a * w0.w;
        acc[4] += a * w1.x; acc[5] += a * w1.y; acc[6] += a * w1.z; acc[7] += a * w1.w;
    }
    float* o = support + (size_t)(row0 + rl) * F_ + f0;
    *(float4*)o       = make_float4(acc[0], acc[1], acc[2], acc[3]);
    *(float4*)(o + 4) = make_float4(acc[4], acc[5], acc[6], acc[7]);
}

// ---------------- Kernel 2: fused attn-GEMM + mask + weighted reduce + residual ----------------
// 4 waves; wave w owns output features f in [32w, 32w+32). MFMA 16x16x32 k-slot fill
// d = ks*32 + (lane>>4)*8 + e identical for A and B (k permutation cancels).
// C/D layout (HW-verified): col = lane&15 (-> f), row = (lane>>4)*4 + reg (-> j).
__global__ __launch_bounds__(256, 2) void fused_kernel(
    const float* __restrict__ op_emb,
    const unsigned* __restrict__ adjw,      // raw 32-bit view of adj (int32 or int64)
    const float* __restrict__ attn_w,
    const float* __restrict__ attn_b,
    const float* __restrict__ self_op,
    const float* __restrict__ support,
    float* __restrict__ out)
{
    __shared__ __align__(16) unsigned short Atile[2][N_ * 64];  // 2 x 12 KB, cols 48..63 zero
    __shared__ __align__(16) float4 jmask[2][N_];  // x: sig-mask, y: const-add, z: self-mask

    const int tid  = threadIdx.x;
    const int lane = tid & 63;
    const int wv   = tid >> 6;      // wave 0..3
    const int lg   = lane >> 4;     // k-slot group / j-subgroup 0..3
    const int lm   = lane & 15;

    const int blk = blockIdx.x;
    const int b   = blk / NGRP;
    const int grp = blk - b * NGRP;
    const int i0  = grp * G_;

    const float kNL2E = -1.44269504088896f;   // -log2(e): exp(-x) = exp2(kNL2E*x)

    // --- adj dtype sniff: int64 little-endian has all-zero high words (values 0..4) ---
    const unsigned probe = adjw[2 * lane + 1];
    const bool use32 = __any(probe != 0);   // wave-uniform; identical across waves

    // --- B fragments (attn_w pre-scaled by -log2e) + bias, registers, once per block ---
    short8 bfrag[2][2];
    float  bbias[2];
    #pragma unroll
    for (int t = 0; t < 2; ++t) {
        const int f = (2 * wv + t) * 16 + lm;
        bbias[t] = attn_b[f] * kNL2E;
        #pragma unroll
        for (int ks = 0; ks < 2; ++ks) {
            short8 v;
            #pragma unroll
            for (int e = 0; e < 8; ++e) {
                const int d = ks * 32 + lg * 8 + e;
                v[e] = (d < D_) ? (short)bfbits(attn_w[d * F_ + f] * kNL2E) : (short)0;
            }
            bfrag[t][ks] = v;
        }
    }

    // --- a_self[t] = sigmoid(self_op . attn_w[:,f] + b[f]) -- (b,i)-independent ---
    float a_self[2];
    {
        float part[2] = {0.f, 0.f};
        #pragma unroll
        for (int ks = 0; ks < 2; ++ks) {
            #pragma unroll
            for (int e = 0; e < 8; ++e) {
                const int d = ks * 32 + lg * 8 + e;
                const float sv = (d < D_) ? self_op[d] : 0.f;
                part[0] = __builtin_fmaf(bf2f((unsigned short)bfrag[0][ks][e]), sv, part[0]);
                part[1] = __builtin_fmaf(bf2f((unsigned short)bfrag[1][ks][e]), sv, part[1]);
            }
        }
        #pragma unroll
        for (int t = 0; t < 2; ++t) {
            float v = part[t];
            v += __shfl_xor(v, 16);
            v += __shfl_xor(v, 32);          // sum over the 4 lg groups -> full 48-dot
            a_self[t] = __builtin_amdgcn_rcpf(1.f + EXP2(v + bbias[t]));
        }
    }

    // --- support fragments, registers, once per block (layout matches C/D frag) ---
    const float* srow = support + (size_t)b * N_ * F_;
    float sfrag[6][4][2];
    #pragma unroll
    for (int mt = 0; mt < 6; ++mt)
        #pragma unroll
        for (int r = 0; r < 4; ++r)
            #pragma unroll
            for (int t = 0; t < 2; ++t)
                sfrag[mt][r][t] = srow[(size_t)(mt * 16 + lg * 4 + r) * F_ + (2 * wv + t) * 16 + lm];

    // --- zero the k-pad (d in [48,64)) of both buffers once ---
    for (int v = tid; v < 2 * N_ * 8; v += 256) {
        const int pb = (v >= N_ * 8) ? 1 : 0;
        const int vv = v - pb * N_ * 8;
        const int j = vv >> 3, c = vv & 7;
        const int byte = j * 128 + ((96 + c * 4) ^ ((j & 7) << 4));
        *(unsigned*)((char*)(&Atile[pb][0]) + byte) = 0u;
    }

    // --- prologue: stage tile 0 + jmask 0 (latency exposed once per block) ---
    {
        const float* tb = op_emb + (size_t)(b * N_ + i0) * (N_ * D_);
        float4 ld[5];
        #pragma unroll
        for (int s = 0; s < 5; ++s) {
            const int w = tid + s * 256;
            if (w < N_ * 12) ld[s] = *(const float4*)(tb + 4 * w);
        }
        int araw = 0;
        if (tid < N_) {
            const size_t idx = (size_t)(b * N_ + i0) * N_ + tid;
            araw = use32 ? (int)adjw[idx] : (int)adjw[2 * idx];
        }
        #pragma unroll
        for (int s = 0; s < 5; ++s) {
            const int w = tid + s * 256;
            if (w < N_ * 12) {
                const int j = w / 12, c = w - 12 * j;
                const int byte = j * 128 + ((c * 8) ^ ((j & 7) << 4));
                *(uint2*)((char*)(&Atile[0][0]) + byte) =
                    make_uint2(bfbits(ld[s].x) | (bfbits(ld[s].y) << 16),
                               bfbits(ld[s].z) | (bfbits(ld[s].w) << 16));
            }
        }
        if (tid < N_) {
            float4 m;
            if (tid == i0) m = make_float4(0.f, (araw == 0) ? 1.f : 0.f, (araw == 0) ? 0.f : 1.f, 0.f);
            else           m = make_float4((araw >= 2) ? 1.f : 0.f, (araw == 1) ? 1.f : 0.f, 0.f, 0.f);
            jmask[0][tid] = m;
        }
    }
    __syncthreads();

    #pragma unroll 1
    for (int g = 0; g < G_; ++g) {
        const int cur = g & 1;
        const int i = i0 + g;
        const bool has_next = (g + 1 < G_);

        // ---- issue next-tile global loads EARLY (results consumed after compute) ----
        float4 ld[5];
        int araw = 0;
        if (has_next) {
            const float* tb = op_emb + (size_t)(b * N_ + (i + 1)) * (N_ * D_);
            #pragma unroll
            for (int s = 0; s < 5; ++s) {
                const int w = tid + s * 256;
                if (w < N_ * 12) ld[s] = *(const float4*)(tb + 4 * w);
            }
            if (tid < N_) {
                const size_t idx = (size_t)(b * N_ + (i + 1)) * N_ + tid;
                araw = use32 ? (int)adjw[idx] : (int)adjw[2 * idx];
            }
        }

        // ---- compute on buffer cur (hides the staging-load latency) ----
        float osum[2] = {0.f, 0.f};
        #pragma unroll
        for (int mt = 0; mt < 6; ++mt) {
            const int jr  = mt * 16 + lm;
            const int swz = (lm & 7) << 4;
            const char* base = (const char*)(&Atile[cur][0]) + jr * 128;
            const short8 a0 = *(const short8*)(base + (( 0 + lg * 16) ^ swz));
            const short8 a1 = *(const short8*)(base + ((64 + lg * 16) ^ swz));
            f32x4 acc0 = (f32x4){bbias[0], bbias[0], bbias[0], bbias[0]};
            f32x4 acc1 = (f32x4){bbias[1], bbias[1], bbias[1], bbias[1]};
            acc0 = __builtin_amdgcn_mfma_f32_16x16x32_bf16(a0, bfrag[0][0], acc0, 0, 0, 0);
            acc0 = __builtin_amdgcn_mfma_f32_16x16x32_bf16(a1, bfrag[0][1], acc0, 0, 0, 0);
            acc1 = __builtin_amdgcn_mfma_f32_16x16x32_bf16(a0, bfrag[1][0], acc1, 0, 0, 0);
            acc1 = __builtin_amdgcn_mfma_f32_16x16x32_bf16(a1, bfrag[1][1], acc1, 0, 0, 0);
            #pragma unroll
            for (int r = 0; r < 4; ++r) {
                const int j = mt * 16 + lg * 4 + r;
                const float4 m = jmask[cur][j];
                const float base0 = __builtin_fmaf(m.z, a_self[0], m.y);
                const float base1 = __builtin_fmaf(m.z, a_self[1], m.y);
                // acc = -log2e*(op_emb.attn_w + b)  ->  sigmoid = rcp(1 + exp2(acc))
                const float sig0 = __builtin_amdgcn_rcpf(1.f + EXP2(acc0[r]));
                const float sig1 = __builtin_amdgcn_rcpf(1.f + EXP2(acc1[r]));
                const float av0 = __builtin_fmaf(m.x, sig0, base0);
                const float av1 = __builtin_fmaf(m.x, sig1, base1);
                osum[0] = __builtin_fmaf(av0, sfrag[mt][r][0], osum[0]);
                osum[1] = __builtin_fmaf(av1, sfrag[mt][r][1], osum[1]);
            }
        }

        // ---- output: lanes {l, l+16, l+32, l+48} hold disjoint j-subsets of same f ----
        #pragma unroll
        for (int t = 0; t < 2; ++t) {
            float v = osum[t];
            v += __shfl_xor(v, 16);
            v += __shfl_xor(v, 32);
            if (lg == 0) {
                const int f = (2 * wv + t) * 16 + lm;
                out[(size_t)(b * N_ + i) * F_ + f] = v + srow[(size_t)i * F_ + f];
            }
        }

        // ---- write next tile to LDS (loads have had the whole compute phase to land) ----
        if (has_next) {
            #pragma unroll
            for (int s = 0; s < 5; ++s) {
                const int w = tid + s * 256;
                if (w < N_ * 12) {
                    const int j = w / 12, c = w - 12 * j;
                    const int byte = j * 128 + ((c * 8) ^ ((j & 7) << 4));
                    *(uint2*)((char*)(&Atile[cur ^ 1][0]) + byte) =
                        make_uint2(bfbits(ld[s].x) | (bfbits(ld[s].y) << 16),
                                   bfbits(ld[s].z) | (bfbits(ld[s].w) << 16));
                }
            }
            if (tid < N_) {
                float4 m;
                const int in = i + 1;
                if (tid == in) m = make_float4(0.f, (araw == 0) ? 1.f : 0.f, (araw == 0) ? 0.f : 1.f, 0.f);
                else           m = make_float4((araw >= 2) ? 1.f : 0.f, (araw == 1) ? 1.f : 0.f, 0.f, 0.f);
                jmask[cur ^ 1][tid] = m;
            }
            __syncthreads();
        }
    }
}

extern "C" void kernel_launch(void* const* d_in, const int* in_sizes, int n_in,
                              void* d_out, int out_size, void* d_ws, size_t ws_size,
                              hipStream_t stream) {
    const float*    inputs  = (const float*)d_in[0];
    const unsigned* adjw    = (const unsigned*)d_in[1];
    const float*    op_emb  = (const float*)d_in[2];
    const float*    weight  = (const float*)d_in[3];
    const float*    attn_w  = (const float*)d_in[4];
    const float*    attn_b  = (const float*)d_in[5];
    const float*    self_op = (const float*)d_in[6];
    float* out     = (float*)d_out;
    float* support = (float*)d_ws;  // 6144*128 fp32 = 3,145,728 bytes

    support_kernel<<<(B_ * N_) / 16, 256, 0, stream>>>(inputs, weight, support);
    fused_kernel<<<B_ * NGRP, 256, 0, stream>>>(op_emb, adjw, attn_w, attn_b, self_op,
                                                support, out);
}